// Round 20
// baseline (2240.676 us; speedup 1.0000x reference)
//
#include <hip/hip_runtime.h>
#include <hip/hip_bf16.h>
#include <math.h>

#define N_NODES 2000
#define N_EDGES 32000
#define H 300
#define CH 75             // H/4 float4 chunks per row
#define HP 320            // padded H for MFMA K/N
#define NLAYERS 30
#define NH (N_NODES * H)     // 600000
#define NODE_ROWS_PAD 2048
#define WMAT (HP * HP)       // 102400 per K-packed matrix
#define NREP 32              // stat replicas
#define RSTRIDE 608          // replica row stride (sum | sumsq at +304)
#define SSTRIDE 304
#define NEB 500              // edge blocks (32000/64)
#define NUB 147              // node_update blocks (1024 chunks each)

typedef short bf16x8 __attribute__((ext_vector_type(8)));
typedef float f32x4 __attribute__((ext_vector_type(4)));
typedef __hip_bfloat16 bf16;

__device__ __forceinline__ float sigm(float x) { return 1.f / (1.f + __expf(-x)); }

// ---------------------------------------------------------------- utilities
__global__ __launch_bounds__(256) void zero_buf(float* __restrict__ p, int n) {
    int i = blockIdx.x * blockDim.x + threadIdx.x;
    if (i < n) p[i] = 0.f;
}

// ---- weights -> bf16, K-packed: WtK[m][ct4][kc][c][j] = W_m[k=kc*8+j][n=ct4*80+c]
__global__ __launch_bounds__(256) void convert_weights_k(const float* __restrict__ eU,
                                                         const float* __restrict__ eW,
                                                         const float* __restrict__ nU,
                                                         const float* __restrict__ nV,
                                                         bf16* __restrict__ WtK) {
    __shared__ float tile[32][33];
    int b = blockIdx.x;                 // 120 mats x 100 tiles
    int m = b / 100;
    int rem = b % 100;
    int kt = rem / 10, nt = rem % 10;
    int k0 = kt * 32, n0 = nt * 32;
    int grp = m / NLAYERS, l = m % NLAYERS;
    const float* S = (grp == 0) ? eU : (grp == 1) ? eW : (grp == 2) ? nU : nV;
    const float* Sl = S + (size_t)l * H * H;
    int t = threadIdx.x;
    int tn = t & 31, tk = t >> 5;
#pragma unroll
    for (int p = 0; p < 4; ++p) {
        int k = tk + p * 8;
        int gk = k0 + k, gn = n0 + tn;
        tile[k][tn] = (gk < H && gn < H) ? Sl[(size_t)gk * H + gn] : 0.f;
    }
    __syncthreads();
    bf16* D = WtK + (size_t)m * WMAT;
    int nn = t >> 3, j8 = t & 7;
    int n = n0 + nn;
    int ct4 = n / 80, c = n % 80;
#pragma unroll
    for (int p = 0; p < 4; ++p) {
        int kc = (k0 >> 3) + p;
        D[(size_t)ct4 * 25600 + (size_t)kc * 640 + c * 8 + j8] =
            __float2bfloat16(tile[p * 8 + j8][nn]);
    }
}

// ------------------------------------------------------------- CSR by dst
__global__ __launch_bounds__(256) void csr_hist(const int* __restrict__ dst,
                                                int* __restrict__ counts) {
    int i = blockIdx.x * 256 + threadIdx.x;
    if (i < N_EDGES) atomicAdd(&counts[dst[i]], 1);
}

__global__ __launch_bounds__(256) void csr_scan(const int* __restrict__ counts,
                                                int* __restrict__ offs,
                                                int* __restrict__ woff) {
    __shared__ int part[256];
    int t = threadIdx.x;
    int base = t * 8;
    int local[8];
    int s = 0;
#pragma unroll
    for (int j = 0; j < 8; ++j) {
        int c = (base + j < N_NODES) ? counts[base + j] : 0;
        local[j] = s;
        s += c;
    }
    part[t] = s;
    __syncthreads();
    for (int off = 1; off < 256; off <<= 1) {
        int v = (t >= off) ? part[t - off] : 0;
        __syncthreads();
        part[t] += v;
        __syncthreads();
    }
    int pre = (t == 0) ? 0 : part[t - 1];
#pragma unroll
    for (int j = 0; j < 8; ++j) {
        int idx = base + j;
        if (idx < N_NODES) { int v = pre + local[j]; offs[idx] = v; woff[idx] = v; }
    }
    if (t == 255) offs[N_NODES] = part[255];
}

// sorted position p <- original edge i; store perm and permuted src/dst
__global__ __launch_bounds__(256) void csr_scatter(const int* __restrict__ src,
                                                   const int* __restrict__ dst,
                                                   int* __restrict__ woff,
                                                   int* __restrict__ eidx,
                                                   int* __restrict__ msrc,
                                                   int* __restrict__ mdst) {
    int i = blockIdx.x * 256 + threadIdx.x;
    if (i < N_EDGES) {
        int d = dst[i];
        int p = atomicAdd(&woff[d], 1);
        eidx[p] = i;
        msrc[p] = src[i];
        mdst[p] = d;
    }
}

// ---------------------------------------------------------------- embeddings
__global__ __launch_bounds__(256) void node_embed(const float* __restrict__ x,
                                                  const float* __restrict__ W,
                                                  const float* __restrict__ b,
                                                  float* __restrict__ node,
                                                  bf16* __restrict__ node_bf) {
    int i = blockIdx.x * blockDim.x + threadIdx.x;
    if (i >= NH) return;
    int n = i / H, h = i % H;
    float acc = b[h];
#pragma unroll
    for (int k = 0; k < 4; ++k) acc += x[n * 4 + k] * W[k * H + h];
    node[i] = acc;
    node_bf[(size_t)n * HP + h] = __float2bfloat16(acc);
}

// edge embedding into SORTED order (row q holds original edge eidx[q])
__global__ __launch_bounds__(256) void edge_embed(const float* __restrict__ ea,
                                                  const int* __restrict__ eidx,
                                                  const float* __restrict__ dW,
                                                  const float* __restrict__ db,
                                                  const float* __restrict__ tW,
                                                  const float* __restrict__ tb,
                                                  bf16* __restrict__ edge_bf,
                                                  float* __restrict__ RS0) {
    __shared__ float s_s[SSTRIDE];
    int t = threadIdx.x;
    for (int i = t; i < SSTRIDE; i += 256) s_s[i] = 0.f;
    __syncthreads();
    int hc = t % 80, rgrp = t / 80;
    int col0 = hc * 4;
    float ss[4] = {0.f, 0.f, 0.f, 0.f};
    if (hc < CH && rgrp < 3) {
        float wv[4], bv[4];
#pragma unroll
        for (int j = 0; j < 4; ++j) {
            int col = col0 + j;
            wv[j] = (col < 150) ? dW[col] : tW[col - 150];
            bv[j] = (col < 150) ? db[col] : tb[col - 150];
        }
        int q0 = blockIdx.x * 64;
        for (int r = rgrp; r < 64; r += 3) {
            int q = q0 + r;
            int e = eidx[q];
            float d = ea[2 * e], tt = ea[2 * e + 1];
            union { ushort4 u; bf16 b[4]; } ob;
#pragma unroll
            for (int j = 0; j < 4; ++j) {
                int col = col0 + j;
                float v = ((col < 150) ? d : tt) * wv[j] + bv[j];
                ob.b[j] = __float2bfloat16(v);
                ss[j] += sigm(__bfloat162float(ob.b[j]));
            }
            *(ushort4*)(edge_bf + (size_t)q * HP + col0) = ob.u;
        }
#pragma unroll
        for (int j = 0; j < 4; ++j) atomicAdd(&s_s[col0 + j], ss[j]);
    }
    __syncthreads();
    float* rs = RS0 + (size_t)(blockIdx.x & (NREP - 1)) * SSTRIDE;
    for (int i = t; i < H; i += 256) atomicAdd(&rs[i], s_s[i]);
}

// ---- K1: node GEMMs (1500 one-wave blocks, K-packed B) + 5 housekeeping blocks
// nodeV written as bf16 (only consumer is the gather branch)
__global__ __launch_bounds__(64) void gemm_node(const bf16* __restrict__ node_bf,
                                                const bf16* __restrict__ WtK_all,
                                                const float* __restrict__ eU_b,
                                                const float* __restrict__ nV_b,
                                                const float* __restrict__ nU_b,
                                                int layer,
                                                float* __restrict__ nodeU,
                                                bf16* __restrict__ nodeV_bf,
                                                float* __restrict__ nodeUn,
                                                const float* __restrict__ RScur,
                                                float* __restrict__ RSnxt,
                                                float* __restrict__ invS) {
    int bx = blockIdx.x;
    int lane = threadIdx.x;
    if (bx >= 1500) {
        int idx = bx - 1500;               // 0..4
        int c = idx * 64 + lane;           // 0..319
        if (c < H) {
            float ssr = 0.f;
#pragma unroll 8
            for (int r = 0; r < NREP; ++r) ssr += RScur[r * SSTRIDE + c];
            invS[c] = 1.f / (ssr + 1e-20f);
        }
        for (int i = idx * 64 + lane; i < NREP * SSTRIDE; i += 320) RSnxt[i] = 0.f;
        return;
    }
    int mat = bx / 500;
    int rem = bx % 500;
    int rt0 = rem >> 2, ct4 = rem & 3;
    int m; const float* bias; float* out;
    if (mat == 0)      { m = layer;      bias = eU_b + layer * H; out = nodeU; }
    else if (mat == 1) { m = 90 + layer; bias = nV_b + layer * H; out = 0; }
    else               { m = 60 + layer; bias = nU_b + layer * H; out = nodeUn; }
    const bf16* Bw = WtK_all + (size_t)m * WMAT + (size_t)ct4 * 25600;
    int row0 = rt0 * 16, c0 = ct4 * 80;
    int rlo = lane & 15, khi = lane >> 4;
    f32x4 acc[5];
#pragma unroll
    for (int ct = 0; ct < 5; ++ct) acc[ct] = (f32x4)0.f;
#pragma unroll 2
    for (int ks = 0; ks < 10; ++ks) {
        int kk = ks * 32 + khi * 8;
        int kcb = (ks * 4 + khi) * 80;
        bf16x8 a, b[5];
        a = *(const bf16x8*)(node_bf + (size_t)(row0 + rlo) * HP + kk);
#pragma unroll
        for (int ct = 0; ct < 5; ++ct)
            b[ct] = *(const bf16x8*)(Bw + (size_t)(kcb + ct * 16 + rlo) * 8);
#pragma unroll
        for (int ct = 0; ct < 5; ++ct)
            acc[ct] = __builtin_amdgcn_mfma_f32_16x16x32_bf16(a, b[ct], acc[ct], 0, 0, 0);
    }
    int rhi = lane >> 4;
#pragma unroll
    for (int ct = 0; ct < 5; ++ct) {
        int col = c0 + ct * 16 + rlo;
        if (col >= H) continue;
        float bv = bias[col];
#pragma unroll
        for (int j = 0; j < 4; ++j) {
            int r = row0 + rhi * 4 + j;
            float v = acc[ct][j] + bv;
            if (mat == 1) nodeV_bf[(size_t)r * H + col] = __float2bfloat16(v);
            else          out[(size_t)r * H + col] = v;
        }
    }
}

// ---- K2 fused: edge gate GEMM (bx<1000) || CSR gather (bx>=1000, 8x unrolled)
__global__ __launch_bounds__(256) void fused_mid(const bf16* __restrict__ edge_bf,
                                                 const bf16* __restrict__ WtK_l,
                                                 const float* __restrict__ nodeU,
                                                 const int* __restrict__ msrc,
                                                 const int* __restrict__ mdst,
                                                 bf16* __restrict__ gate_bf,
                                                 float* __restrict__ REc,
                                                 const bf16* __restrict__ nodeV_bf,
                                                 const float* __restrict__ nodeUn,
                                                 const int* __restrict__ offs,
                                                 const float* __restrict__ invS,
                                                 float* __restrict__ RNc,
                                                 float* __restrict__ aggv) {
    __shared__ bf16 smA[32 * 320];         // 20 KB
    int tid = threadIdx.x;
    int bx = blockIdx.x;
    if (bx < 1000) {
        int wave = tid >> 6, lane = tid & 63;
        int row0 = bx * 32;
        int c0 = wave * 80;
        int rlo = lane & 15, khi = lane >> 4, rhi = lane >> 4;

        // hoist permuted src/dst loads (coalesced)
        int se_[8], de_[8];
#pragma unroll
        for (int rt = 0; rt < 2; ++rt)
#pragma unroll
            for (int j = 0; j < 4; ++j) {
                int r = row0 + rt * 16 + rhi * 4 + j;
                se_[rt * 4 + j] = msrc[r];
                de_[rt * 4 + j] = mdst[r];
            }

        // stage A: fully coalesced 20480B contiguous span, XOR-swizzled
        const uint4* Ag = (const uint4*)(edge_bf + (size_t)row0 * HP);
#pragma unroll
        for (int it = 0; it < 5; ++it) {
            int cid = it * 256 + tid;      // 0..1279
            int row = cid / 40, ch = cid % 40;
            uint4 v = Ag[cid];
            *(uint4*)(smA + row * 320 + ((ch ^ (row & 7)) << 3)) = v;
        }
        __syncthreads();

        const bf16* Bw = WtK_l + (size_t)wave * 25600;
        f32x4 acc[2][5];
#pragma unroll
        for (int rt = 0; rt < 2; ++rt)
#pragma unroll
            for (int ct = 0; ct < 5; ++ct) acc[rt][ct] = (f32x4)0.f;
#pragma unroll 2
        for (int ks = 0; ks < 10; ++ks) {
            int c = ks * 4 + khi;
            int kcb = (ks * 4 + khi) * 80;
            bf16x8 a[2], b[5];
#pragma unroll
            for (int rt = 0; rt < 2; ++rt) {
                int row = rt * 16 + rlo;
                a[rt] = *(const bf16x8*)(smA + row * 320 + ((c ^ (row & 7)) << 3));
            }
#pragma unroll
            for (int ct = 0; ct < 5; ++ct)
                b[ct] = *(const bf16x8*)(Bw + (size_t)(kcb + ct * 16 + rlo) * 8);
#pragma unroll
            for (int rt = 0; rt < 2; ++rt)
#pragma unroll
                for (int ct = 0; ct < 5; ++ct)
                    acc[rt][ct] = __builtin_amdgcn_mfma_f32_16x16x32_bf16(a[rt], b[ct], acc[rt][ct], 0, 0, 0);
        }
        float csum[5], csq[5];
#pragma unroll
        for (int ct = 0; ct < 5; ++ct) { csum[ct] = 0.f; csq[ct] = 0.f; }
#pragma unroll
        for (int rt = 0; rt < 2; ++rt)
#pragma unroll
            for (int j = 0; j < 4; ++j) {
                int r = row0 + rt * 16 + rhi * 4 + j;
                int se = se_[rt * 4 + j], de = de_[rt * 4 + j];
#pragma unroll
                for (int ct = 0; ct < 5; ++ct) {
                    int col = c0 + ct * 16 + rlo;
                    if (col < H) {
                        float g = acc[rt][ct][j] + nodeU[(size_t)se * H + col] + nodeU[(size_t)de * H + col];
                        gate_bf[(size_t)r * H + col] = __float2bfloat16(g);
                        csum[ct] += g;
                        csq[ct] += g * g;
                    }
                }
            }
#pragma unroll
        for (int ct = 0; ct < 5; ++ct) {
            csum[ct] += __shfl_xor(csum[ct], 16, 64);
            csum[ct] += __shfl_xor(csum[ct], 32, 64);
            csq[ct]  += __shfl_xor(csq[ct], 16, 64);
            csq[ct]  += __shfl_xor(csq[ct], 32, 64);
        }
        if (khi == 0) {
            float* re = REc + (size_t)(bx & (NREP - 1)) * RSTRIDE;
#pragma unroll
            for (int ct = 0; ct < 5; ++ct) {
                int col = c0 + ct * 16 + rlo;
                if (col < H) {
                    atomicAdd(&re[col], csum[ct]);
                    atomicAdd(&re[SSTRIDE + col], csq[ct]);
                }
            }
        }
    } else {
        // ------- CSR gather: 1 node/block; contiguous rows; 8x unrolled ILP
        int n = bx - 1000;                 // 0..1999
        int h0 = tid;
        bool has1 = (tid < H - 256);
        int h1 = 256 + tid;
        float inv0 = invS[h0];
        float inv1 = has1 ? invS[h1] : 0.f;
        int beg = offs[n], end = offs[n + 1];
        float a0 = 0.f, a1 = 0.f, a2 = 0.f, a3 = 0.f;
        float a4 = 0.f, a5 = 0.f, a6 = 0.f, a7 = 0.f;
        float b0 = 0.f, b1 = 0.f, b2 = 0.f, b3 = 0.f;
        float b4 = 0.f, b5 = 0.f, b6 = 0.f, b7 = 0.f;
        int i = beg;
        for (; i + 8 <= end; i += 8) {
            int s0 = msrc[i],     s1_ = msrc[i + 1], s2_ = msrc[i + 2], s3_ = msrc[i + 3];
            int s4 = msrc[i + 4], s5_ = msrc[i + 5], s6_ = msrc[i + 6], s7_ = msrc[i + 7];
            const bf16* e0 = edge_bf + (size_t)(i + 0) * HP;
            const bf16* e1 = edge_bf + (size_t)(i + 1) * HP;
            const bf16* e2 = edge_bf + (size_t)(i + 2) * HP;
            const bf16* e3 = edge_bf + (size_t)(i + 3) * HP;
            const bf16* e4 = edge_bf + (size_t)(i + 4) * HP;
            const bf16* e5 = edge_bf + (size_t)(i + 5) * HP;
            const bf16* e6 = edge_bf + (size_t)(i + 6) * HP;
            const bf16* e7 = edge_bf + (size_t)(i + 7) * HP;
            const bf16* v0 = nodeV_bf + (size_t)s0 * H;
            const bf16* v1 = nodeV_bf + (size_t)s1_ * H;
            const bf16* v2 = nodeV_bf + (size_t)s2_ * H;
            const bf16* v3 = nodeV_bf + (size_t)s3_ * H;
            const bf16* v4 = nodeV_bf + (size_t)s4 * H;
            const bf16* v5 = nodeV_bf + (size_t)s5_ * H;
            const bf16* v6 = nodeV_bf + (size_t)s6_ * H;
            const bf16* v7 = nodeV_bf + (size_t)s7_ * H;
            a0 += sigm(__bfloat162float(e0[h0])) * __bfloat162float(v0[h0]);
            a1 += sigm(__bfloat162float(e1[h0])) * __bfloat162float(v1[h0]);
            a2 += sigm(__bfloat162float(e2[h0])) * __bfloat162float(v2[h0]);
            a3 += sigm(__bfloat162float(e3[h0])) * __bfloat162float(v3[h0]);
            a4 += sigm(__bfloat162float(e4[h0])) * __bfloat162float(v4[h0]);
            a5 += sigm(__bfloat162float(e5[h0])) * __bfloat162float(v5[h0]);
            a6 += sigm(__bfloat162float(e6[h0])) * __bfloat162float(v6[h0]);
            a7 += sigm(__bfloat162float(e7[h0])) * __bfloat162float(v7[h0]);
            if (has1) {
                b0 += sigm(__bfloat162float(e0[h1])) * __bfloat162float(v0[h1]);
                b1 += sigm(__bfloat162float(e1[h1])) * __bfloat162float(v1[h1]);
                b2 += sigm(__bfloat162float(e2[h1])) * __bfloat162float(v2[h1]);
                b3 += sigm(__bfloat162float(e3[h1])) * __bfloat162float(v3[h1]);
                b4 += sigm(__bfloat162float(e4[h1])) * __bfloat162float(v4[h1]);
                b5 += sigm(__bfloat162float(e5[h1])) * __bfloat162float(v5[h1]);
                b6 += sigm(__bfloat162float(e6[h1])) * __bfloat162float(v6[h1]);
                b7 += sigm(__bfloat162float(e7[h1])) * __bfloat162float(v7[h1]);
            }
        }
        for (; i + 4 <= end; i += 4) {
            int s0 = msrc[i], s1_ = msrc[i + 1], s2_ = msrc[i + 2], s3_ = msrc[i + 3];
            const bf16* e0 = edge_bf + (size_t)(i + 0) * HP;
            const bf16* e1 = edge_bf + (size_t)(i + 1) * HP;
            const bf16* e2 = edge_bf + (size_t)(i + 2) * HP;
            const bf16* e3 = edge_bf + (size_t)(i + 3) * HP;
            const bf16* v0 = nodeV_bf + (size_t)s0 * H;
            const bf16* v1 = nodeV_bf + (size_t)s1_ * H;
            const bf16* v2 = nodeV_bf + (size_t)s2_ * H;
            const bf16* v3 = nodeV_bf + (size_t)s3_ * H;
            a0 += sigm(__bfloat162float(e0[h0])) * __bfloat162float(v0[h0]);
            a1 += sigm(__bfloat162float(e1[h0])) * __bfloat162float(v1[h0]);
            a2 += sigm(__bfloat162float(e2[h0])) * __bfloat162float(v2[h0]);
            a3 += sigm(__bfloat162float(e3[h0])) * __bfloat162float(v3[h0]);
            if (has1) {
                b0 += sigm(__bfloat162float(e0[h1])) * __bfloat162float(v0[h1]);
                b1 += sigm(__bfloat162float(e1[h1])) * __bfloat162float(v1[h1]);
                b2 += sigm(__bfloat162float(e2[h1])) * __bfloat162float(v2[h1]);
                b3 += sigm(__bfloat162float(e3[h1])) * __bfloat162float(v3[h1]);
            }
        }
        for (; i < end; ++i) {
            int s = msrc[i];
            const bf16* er = edge_bf + (size_t)i * HP;
            const bf16* vr = nodeV_bf + (size_t)s * H;
            a0 += sigm(__bfloat162float(er[h0])) * __bfloat162float(vr[h0]);
            if (has1) b0 += sigm(__bfloat162float(er[h1])) * __bfloat162float(vr[h1]);
        }
        float a = ((a0 + a1) + (a2 + a3)) + ((a4 + a5) + (a6 + a7));
        size_t nbase = (size_t)n * H;
        float v0s = nodeUn[nbase + h0] + a * inv0;
        aggv[nbase + h0] = v0s;
        float* rn = RNc + (size_t)(n & (NREP - 1)) * RSTRIDE;
        atomicAdd(&rn[h0], v0s);
        atomicAdd(&rn[SSTRIDE + h0], v0s * v0s);
        if (has1) {
            float bsum = ((b0 + b1) + (b2 + b3)) + ((b4 + b5) + (b6 + b7));
            float v1s = nodeUn[nbase + h1] + bsum * inv1;
            aggv[nbase + h1] = v1s;
            atomicAdd(&rn[h1], v1s);
            atomicAdd(&rn[SSTRIDE + h1], v1s * v1s);
        }
    }
}

// ------------- K3: edge_finalize (bx<NEB) || node_update (bx>=NEB), bf16 residual
__global__ __launch_bounds__(256) void fused_final(bf16* __restrict__ edge_bf,
                                                   const bf16* __restrict__ gate_bf,
                                                   const float* __restrict__ REc,
                                                   float* __restrict__ REo,
                                                   const float* __restrict__ RNc,
                                                   float* __restrict__ RNo,
                                                   float* __restrict__ RSnext,
                                                   const float* __restrict__ eg,
                                                   const float* __restrict__ ebt,
                                                   const float* __restrict__ ng,
                                                   const float* __restrict__ nbt,
                                                   float* __restrict__ node,
                                                   bf16* __restrict__ node_bf,
                                                   const float* __restrict__ aggv) {
    __shared__ float sc_s[SSTRIDE], of_s[SSTRIDE], s_s[SSTRIDE];
    int bx = blockIdx.x, t = threadIdx.x;
    if (bx < NEB) {
        const float invE = 1.f / N_EDGES;
        for (int i = t; i < SSTRIDE; i += 256) {
            s_s[i] = 0.f;
            if (i < H) {
                float gs = 0.f, gq = 0.f;
#pragma unroll 8
                for (int r = 0; r < NREP; ++r) {
                    gs += REc[r * RSTRIDE + i];
                    gq += REc[r * RSTRIDE + SSTRIDE + i];
                }
                float mean = gs * invE;
                float var = fmaxf(gq * invE - mean * mean, 0.f);
                float rstd = rsqrtf(var + 1e-5f);
                float sc = rstd * eg[i];
                sc_s[i] = sc;
                of_s[i] = ebt[i] - mean * sc;
            }
        }
        __syncthreads();
        int hc = t % 80, rgrp = t / 80;
        bool act = (hc < CH) && (rgrp < 3);
        float ss[4] = {0.f, 0.f, 0.f, 0.f};
        int col0 = hc * 4;
        if (act) {
            float sc[4], of[4];
#pragma unroll
            for (int j = 0; j < 4; ++j) { sc[j] = sc_s[col0 + j]; of[j] = of_s[col0 + j]; }
            int e0 = bx * 64;
            for (int r = rgrp; r < 64; r += 3) {
                int e = e0 + r;
                union { ushort4 u; bf16 b[4]; } eb, gv, ob;
                eb.u = *(const ushort4*)(edge_bf + (size_t)e * HP + col0);
                gv.u = *(const ushort4*)(gate_bf + (size_t)e * H + col0);
#pragma unroll
                for (int j = 0; j < 4; ++j) {
                    float g = __bfloat162float(gv.b[j]);
                    float val = fmaxf(fmaf(g, sc[j], of[j]), 0.f);
                    float nv = __bfloat162float(eb.b[j]) + val;
                    ob.b[j] = __float2bfloat16(nv);
                    ss[j] += sigm(__bfloat162float(ob.b[j]));
                }
                *(ushort4*)(edge_bf + (size_t)e * HP + col0) = ob.u;
            }
#pragma unroll
            for (int j = 0; j < 4; ++j) atomicAdd(&s_s[col0 + j], ss[j]);
        }
        __syncthreads();
        float* rs = RSnext + (size_t)(bx & (NREP - 1)) * SSTRIDE;
        for (int i = t; i < H; i += 256) atomicAdd(&rs[i], s_s[i]);
    } else {
        int idx = bx - NEB;                // 0..NUB-1
        if (idx < NREP) {
            for (int i = t; i < RSTRIDE; i += 256) {
                REo[(size_t)idx * RSTRIDE + i] = 0.f;
                RNo[(size_t)idx * RSTRIDE + i] = 0.f;
            }
        }
        const float invN = 1.f / N_NODES;
        for (int i = t; i < H; i += 256) {
            float ns = 0.f, nq = 0.f;
#pragma unroll 8
            for (int r = 0; r < NREP; ++r) {
                ns += RNc[r * RSTRIDE + i];
                nq += RNc[r * RSTRIDE + SSTRIDE + i];
            }
            float mean = ns * invN;
            float var = fmaxf(nq * invN - mean * mean, 0.f);
            float rstd = rsqrtf(var + 1e-5f);
            float sc = rstd * ng[i];
            sc_s[i] = sc;
            of_s[i] = nbt[i] - mean * sc;
        }
        __syncthreads();
#pragma unroll
        for (int it = 0; it < 4; ++it) {
            int c = idx * 1024 + it * 256 + t;
            if (c >= NH / 4) break;
            int n = c / CH, hc = c % CH, col0 = hc * 4;
            float4 v4 = ((const float4*)aggv)[c];
            float4 nd = ((const float4*)node)[c];
            const float* v4p = (const float*)&v4;
            const float* ndp = (const float*)&nd;
            union { ushort4 u; bf16 b[4]; } ob;
            float outv[4];
#pragma unroll
            for (int j = 0; j < 4; ++j) {
                float g = fmaf(v4p[j], sc_s[col0 + j], of_s[col0 + j]);
                outv[j] = ndp[j] + fmaxf(g, 0.f);
                ob.b[j] = __float2bfloat16(outv[j]);
            }
            ((float4*)node)[c] = make_float4(outv[0], outv[1], outv[2], outv[3]);
            *(ushort4*)(node_bf + (size_t)n * HP + col0) = ob.u;
        }
    }
}

// ----------------- classifier + loss (sorted rows; map back via eidx)
__global__ __launch_bounds__(256) void classify_loss(const bf16* __restrict__ edge_bf,
                                                     const float* __restrict__ clsW,
                                                     const float* __restrict__ clsb,
                                                     const int* __restrict__ eidx,
                                                     const int* __restrict__ msrc,
                                                     const int* __restrict__ mdst,
                                                     const float* __restrict__ y,
                                                     float* __restrict__ out) {
    __shared__ float wl[4];
    int lane = threadIdx.x & 63;
    int wid = threadIdx.x >> 6;
    int quad = lane >> 2;
    int ql = lane & 3;
    float w[80];
#pragma unroll
    for (int j = 0; j < 80; ++j) {
        int col = ql * 80 + j;
        w[j] = (col < H) ? clsW[col] : 0.f;
    }
    int g = blockIdx.x * 4 + wid;
    int q = g * 16 + quad;             // sorted row index
    const bf16* row = edge_bf + (size_t)q * HP + ql * 80;
    float acc = 0.f;
#pragma unroll
    for (int v = 0; v < 10; ++v) {
        bf16x8 bv = *(const bf16x8*)(row + v * 8);
#pragma unroll
        for (int j = 0; j < 8; ++j)
            acc += __bfloat162float(((const bf16*)&bv)[j]) * w[v * 8 + j];
    }
    acc += __shfl_xor(acc, 1, 64);
    acc += __shfl_xor(acc, 2, 64);
    float lsum = 0.f;
    if (ql == 0) {
        float z = acc + clsb[0];
        float p = 1.f / (1.f + __expf(-z));
        atomicAdd(&out[(size_t)msrc[q] * N_NODES + mdst[q]], p);
        float yv = y[eidx[q]];
        float pc = fminf(fmaxf(p, 1e-7f), 1.f - 1e-7f);
        lsum = -(yv * __logf(pc) + (1.f - yv) * log1pf(-pc));
    }
#pragma unroll
    for (int off = 32; off > 0; off >>= 1) lsum += __shfl_down(lsum, off, 64);
    if (lane == 0) wl[wid] = lsum;
    __syncthreads();
    if (threadIdx.x == 0) {
        float tt = wl[0] + wl[1] + wl[2] + wl[3];
        atomicAdd(&out[(size_t)N_NODES * N_NODES], tt * (1.f / N_EDGES));
    }
}

// ---------------------------------------------------------------- launcher
extern "C" void kernel_launch(void* const* d_in, const int* in_sizes, int n_in,
                              void* d_out, int out_size, void* d_ws, size_t ws_size,
                              hipStream_t stream) {
    const float* x          = (const float*)d_in[0];
    const float* edge_attr  = (const float*)d_in[1];
    const int*   edge_index = (const int*)d_in[2];
    const float* y          = (const float*)d_in[3];
    const float* node_emb_W = (const float*)d_in[4];
    const float* node_emb_b = (const float*)d_in[5];
    const float* edge_d_W   = (const float*)d_in[6];
    const float* edge_d_b   = (const float*)d_in[7];
    const float* edge_t_W   = (const float*)d_in[8];
    const float* edge_t_b   = (const float*)d_in[9];
    const float* eU_W = (const float*)d_in[10];
    const float* eU_b = (const float*)d_in[11];
    const float* eW_W = (const float*)d_in[12];
    const float* nU_W = (const float*)d_in[14];
    const float* nU_b = (const float*)d_in[15];
    const float* nV_W = (const float*)d_in[16];
    const float* nV_b = (const float*)d_in[17];
    const float* bn_e_g = (const float*)d_in[18];
    const float* bn_e_b = (const float*)d_in[19];
    const float* bn_n_g = (const float*)d_in[20];
    const float* bn_n_b = (const float*)d_in[21];
    const float* cls_W = (const float*)d_in[22];
    const float* cls_b = (const float*)d_in[23];

    const int* src = edge_index;
    const int* dst = edge_index + N_EDGES;

    float* ws     = (float*)d_ws;
    float* node   = ws;                  // NH
    float* nodeU  = node + NH;           // NH
    float* nodeV  = nodeU + NH;          // NH (bf16 actually; reuse slot)
    float* nodeUn = nodeV + NH;          // NH
    float* aggv   = nodeUn + NH;         // NH
    float* RE2    = aggv + NH;           // 2 x 32*608   <-- zero region start
    float* RN2    = RE2 + 2 * NREP * RSTRIDE;
    float* RS2    = RN2 + 2 * NREP * RSTRIDE;  // 2 x 32*304
    float* invS   = RS2 + 2 * NREP * SSTRIDE;  // 304
    bf16* nodeV_bf = (bf16*)nodeV;                        // 2000*300 bf16 (in nodeV slot)
    bf16* node_bf = (bf16*)(invS + SSTRIDE);              // 2048*320
    bf16* edge_bf = node_bf + (size_t)NODE_ROWS_PAD * HP; // 32000*320 (sorted order)
    bf16* gate_bf = edge_bf + (size_t)N_EDGES * HP;       // 32000*300 (not zeroed)
    bf16* WtK_all = gate_bf + (size_t)N_EDGES * H;        // 120*102400 (K-packed)
    int* csr_counts = (int*)(WtK_all + (size_t)120 * WMAT);
    int* csr_offs   = csr_counts + 2048;
    int* csr_woff   = csr_offs + 2048;
    int* csr_eidx   = csr_woff + 2048;                     // 32000
    int* csr_msrc   = csr_eidx + N_EDGES;                  // 32000
    int* csr_mdst   = csr_msrc + N_EDGES;                  // 32000

    float* out = (float*)d_out;

    // zero: out, [RE2 | RN2 | RS2 | invS | node_bf | edge_bf], csr_counts
    int zstats = 4 * NREP * RSTRIDE + 2 * NREP * SSTRIDE + SSTRIDE;
    int zlen = zstats + (NODE_ROWS_PAD * HP + N_EDGES * HP) / 2;
    zero_buf<<<(N_NODES * N_NODES + 1 + 255) / 256, 256, 0, stream>>>(out, N_NODES * N_NODES + 1);
    zero_buf<<<(zlen + 255) / 256, 256, 0, stream>>>(RE2, zlen);
    zero_buf<<<8, 256, 0, stream>>>((float*)csr_counts, 2048);

    convert_weights_k<<<12000, 256, 0, stream>>>(eU_W, eW_W, nU_W, nV_W, WtK_all);
    csr_hist<<<(N_EDGES + 255) / 256, 256, 0, stream>>>(dst, csr_counts);
    csr_scan<<<1, 256, 0, stream>>>(csr_counts, csr_offs, csr_woff);
    csr_scatter<<<(N_EDGES + 255) / 256, 256, 0, stream>>>(src, dst, csr_woff,
                                                           csr_eidx, csr_msrc, csr_mdst);
    node_embed<<<(NH + 255) / 256, 256, 0, stream>>>(x, node_emb_W, node_emb_b, node, node_bf);
    edge_embed<<<NEB, 256, 0, stream>>>(edge_attr, csr_eidx, edge_d_W, edge_d_b,
                                        edge_t_W, edge_t_b, edge_bf, RS2);

    for (int l = 0; l < NLAYERS; ++l) {
        float* REc = RE2 + (size_t)(l & 1) * NREP * RSTRIDE;
        float* REo = RE2 + (size_t)((l + 1) & 1) * NREP * RSTRIDE;
        float* RNc = RN2 + (size_t)(l & 1) * NREP * RSTRIDE;
        float* RNo = RN2 + (size_t)((l + 1) & 1) * NREP * RSTRIDE;
        float* RScur = RS2 + (size_t)(l & 1) * NREP * SSTRIDE;
        float* RSnxt = RS2 + (size_t)((l + 1) & 1) * NREP * SSTRIDE;
        const bf16* WtK_e = WtK_all + (size_t)(30 + l) * WMAT;

        gemm_node<<<1505, 64, 0, stream>>>(node_bf, WtK_all, eU_b, nV_b, nU_b, l,
                                           nodeU, nodeV_bf, nodeUn, RScur, RSnxt, invS);
        fused_mid<<<3000, 256, 0, stream>>>(edge_bf, WtK_e, nodeU, csr_msrc, csr_mdst,
                                            gate_bf, REc,
                                            nodeV_bf, nodeUn, csr_offs,
                                            invS, RNc, aggv);
        fused_final<<<NEB + NUB, 256, 0, stream>>>(edge_bf, gate_bf,
                                                   REc, REo, RNc, RNo, RSnxt,
                                                   bn_e_g + l * H, bn_e_b + l * H,
                                                   bn_n_g + l * H, bn_n_b + l * H,
                                                   node, node_bf, aggv);
    }

    classify_loss<<<500, 256, 0, stream>>>(edge_bf, cls_W, cls_b,
                                           csr_eidx, csr_msrc, csr_mdst, y, out);
}

// Round 21
// 2095.542 us; speedup vs baseline: 1.0693x; 1.0693x over previous
//
#include <hip/hip_runtime.h>
#include <hip/hip_bf16.h>
#include <math.h>

#define N_NODES 2000
#define N_EDGES 32000
#define H 300
#define CH 75             // H/4 float4 chunks per row
#define HP 320            // padded H for MFMA K/N
#define NLAYERS 30
#define NH (N_NODES * H)     // 600000
#define NODE_ROWS_PAD 2048
#define WMAT (HP * HP)       // 102400 per K-packed matrix
#define NREP 32              // stat replicas
#define RSTRIDE 608          // replica row stride (sum | sumsq at +304)
#define SSTRIDE 304
#define NEB 500              // edge blocks (32000/64)
#define NUB 147              // node_update blocks (1024 chunks each)

typedef short bf16x8 __attribute__((ext_vector_type(8)));
typedef float f32x4 __attribute__((ext_vector_type(4)));
typedef __hip_bfloat16 bf16;

__device__ __forceinline__ float sigm(float x) { return 1.f / (1.f + __expf(-x)); }

// ---------------------------------------------------------------- utilities
__global__ __launch_bounds__(256) void zero_buf(float* __restrict__ p, int n) {
    int i = blockIdx.x * blockDim.x + threadIdx.x;
    if (i < n) p[i] = 0.f;
}

// ---- weights -> bf16, K-packed: WtK[m][ct4][kc][c][j] = W_m[k=kc*8+j][n=ct4*80+c]
__global__ __launch_bounds__(256) void convert_weights_k(const float* __restrict__ eU,
                                                         const float* __restrict__ eW,
                                                         const float* __restrict__ nU,
                                                         const float* __restrict__ nV,
                                                         bf16* __restrict__ WtK) {
    __shared__ float tile[32][33];
    int b = blockIdx.x;                 // 120 mats x 100 tiles
    int m = b / 100;
    int rem = b % 100;
    int kt = rem / 10, nt = rem % 10;
    int k0 = kt * 32, n0 = nt * 32;
    int grp = m / NLAYERS, l = m % NLAYERS;
    const float* S = (grp == 0) ? eU : (grp == 1) ? eW : (grp == 2) ? nU : nV;
    const float* Sl = S + (size_t)l * H * H;
    int t = threadIdx.x;
    int tn = t & 31, tk = t >> 5;
#pragma unroll
    for (int p = 0; p < 4; ++p) {
        int k = tk + p * 8;
        int gk = k0 + k, gn = n0 + tn;
        tile[k][tn] = (gk < H && gn < H) ? Sl[(size_t)gk * H + gn] : 0.f;
    }
    __syncthreads();
    bf16* D = WtK + (size_t)m * WMAT;
    int nn = t >> 3, j8 = t & 7;
    int n = n0 + nn;
    int ct4 = n / 80, c = n % 80;
#pragma unroll
    for (int p = 0; p < 4; ++p) {
        int kc = (k0 >> 3) + p;
        D[(size_t)ct4 * 25600 + (size_t)kc * 640 + c * 8 + j8] =
            __float2bfloat16(tile[p * 8 + j8][nn]);
    }
}

// ------------------------------------------------------------- CSR by dst
__global__ __launch_bounds__(256) void csr_hist(const int* __restrict__ dst,
                                                int* __restrict__ counts) {
    int i = blockIdx.x * 256 + threadIdx.x;
    if (i < N_EDGES) atomicAdd(&counts[dst[i]], 1);
}

__global__ __launch_bounds__(256) void csr_scan(const int* __restrict__ counts,
                                                int* __restrict__ offs,
                                                int* __restrict__ woff) {
    __shared__ int part[256];
    int t = threadIdx.x;
    int base = t * 8;
    int local[8];
    int s = 0;
#pragma unroll
    for (int j = 0; j < 8; ++j) {
        int c = (base + j < N_NODES) ? counts[base + j] : 0;
        local[j] = s;
        s += c;
    }
    part[t] = s;
    __syncthreads();
    for (int off = 1; off < 256; off <<= 1) {
        int v = (t >= off) ? part[t - off] : 0;
        __syncthreads();
        part[t] += v;
        __syncthreads();
    }
    int pre = (t == 0) ? 0 : part[t - 1];
#pragma unroll
    for (int j = 0; j < 8; ++j) {
        int idx = base + j;
        if (idx < N_NODES) { int v = pre + local[j]; offs[idx] = v; woff[idx] = v; }
    }
    if (t == 255) offs[N_NODES] = part[255];
}

// sorted position p <- original edge i; store perm and permuted src/dst
__global__ __launch_bounds__(256) void csr_scatter(const int* __restrict__ src,
                                                   const int* __restrict__ dst,
                                                   int* __restrict__ woff,
                                                   int* __restrict__ eidx,
                                                   int* __restrict__ msrc,
                                                   int* __restrict__ mdst) {
    int i = blockIdx.x * 256 + threadIdx.x;
    if (i < N_EDGES) {
        int d = dst[i];
        int p = atomicAdd(&woff[d], 1);
        eidx[p] = i;
        msrc[p] = src[i];
        mdst[p] = d;
    }
}

// ---------------------------------------------------------------- embeddings
__global__ __launch_bounds__(256) void node_embed(const float* __restrict__ x,
                                                  const float* __restrict__ W,
                                                  const float* __restrict__ b,
                                                  float* __restrict__ node,
                                                  bf16* __restrict__ node_bf) {
    int i = blockIdx.x * blockDim.x + threadIdx.x;
    if (i >= NH) return;
    int n = i / H, h = i % H;
    float acc = b[h];
#pragma unroll
    for (int k = 0; k < 4; ++k) acc += x[n * 4 + k] * W[k * H + h];
    node[i] = acc;
    node_bf[(size_t)n * HP + h] = __float2bfloat16(acc);
}

// edge embedding into SORTED order (row q holds original edge eidx[q])
__global__ __launch_bounds__(256) void edge_embed(const float* __restrict__ ea,
                                                  const int* __restrict__ eidx,
                                                  const float* __restrict__ dW,
                                                  const float* __restrict__ db,
                                                  const float* __restrict__ tW,
                                                  const float* __restrict__ tb,
                                                  bf16* __restrict__ edge_bf,
                                                  float* __restrict__ RS0) {
    __shared__ float s_s[SSTRIDE];
    int t = threadIdx.x;
    for (int i = t; i < SSTRIDE; i += 256) s_s[i] = 0.f;
    __syncthreads();
    int hc = t % 80, rgrp = t / 80;
    int col0 = hc * 4;
    float ss[4] = {0.f, 0.f, 0.f, 0.f};
    if (hc < CH && rgrp < 3) {
        float wv[4], bv[4];
#pragma unroll
        for (int j = 0; j < 4; ++j) {
            int col = col0 + j;
            wv[j] = (col < 150) ? dW[col] : tW[col - 150];
            bv[j] = (col < 150) ? db[col] : tb[col - 150];
        }
        int q0 = blockIdx.x * 64;
        for (int r = rgrp; r < 64; r += 3) {
            int q = q0 + r;
            int e = eidx[q];
            float d = ea[2 * e], tt = ea[2 * e + 1];
            union { ushort4 u; bf16 b[4]; } ob;
#pragma unroll
            for (int j = 0; j < 4; ++j) {
                int col = col0 + j;
                float v = ((col < 150) ? d : tt) * wv[j] + bv[j];
                ob.b[j] = __float2bfloat16(v);
                ss[j] += sigm(__bfloat162float(ob.b[j]));
            }
            *(ushort4*)(edge_bf + (size_t)q * HP + col0) = ob.u;
        }
#pragma unroll
        for (int j = 0; j < 4; ++j) atomicAdd(&s_s[col0 + j], ss[j]);
    }
    __syncthreads();
    float* rs = RS0 + (size_t)(blockIdx.x & (NREP - 1)) * SSTRIDE;
    for (int i = t; i < H; i += 256) atomicAdd(&rs[i], s_s[i]);
}

// ---- K1: node GEMMs (1500 one-wave blocks, K-packed B) + 5 housekeeping blocks
// nodeV written as bf16 (only consumer is the gather branch)
__global__ __launch_bounds__(64) void gemm_node(const bf16* __restrict__ node_bf,
                                                const bf16* __restrict__ WtK_all,
                                                const float* __restrict__ eU_b,
                                                const float* __restrict__ nV_b,
                                                const float* __restrict__ nU_b,
                                                int layer,
                                                float* __restrict__ nodeU,
                                                bf16* __restrict__ nodeV_bf,
                                                float* __restrict__ nodeUn,
                                                const float* __restrict__ RScur,
                                                float* __restrict__ RSnxt,
                                                float* __restrict__ invS) {
    int bx = blockIdx.x;
    int lane = threadIdx.x;
    if (bx >= 1500) {
        int idx = bx - 1500;               // 0..4
        int c = idx * 64 + lane;           // 0..319
        if (c < H) {
            float ssr = 0.f;
#pragma unroll 8
            for (int r = 0; r < NREP; ++r) ssr += RScur[r * SSTRIDE + c];
            invS[c] = 1.f / (ssr + 1e-20f);
        }
        for (int i = idx * 64 + lane; i < NREP * SSTRIDE; i += 320) RSnxt[i] = 0.f;
        return;
    }
    int mat = bx / 500;
    int rem = bx % 500;
    int rt0 = rem >> 2, ct4 = rem & 3;
    int m; const float* bias; float* out;
    if (mat == 0)      { m = layer;      bias = eU_b + layer * H; out = nodeU; }
    else if (mat == 1) { m = 90 + layer; bias = nV_b + layer * H; out = 0; }
    else               { m = 60 + layer; bias = nU_b + layer * H; out = nodeUn; }
    const bf16* Bw = WtK_all + (size_t)m * WMAT + (size_t)ct4 * 25600;
    int row0 = rt0 * 16, c0 = ct4 * 80;
    int rlo = lane & 15, khi = lane >> 4;
    f32x4 acc[5];
#pragma unroll
    for (int ct = 0; ct < 5; ++ct) acc[ct] = (f32x4)0.f;
#pragma unroll 2
    for (int ks = 0; ks < 10; ++ks) {
        int kk = ks * 32 + khi * 8;
        int kcb = (ks * 4 + khi) * 80;
        bf16x8 a, b[5];
        a = *(const bf16x8*)(node_bf + (size_t)(row0 + rlo) * HP + kk);
#pragma unroll
        for (int ct = 0; ct < 5; ++ct)
            b[ct] = *(const bf16x8*)(Bw + (size_t)(kcb + ct * 16 + rlo) * 8);
#pragma unroll
        for (int ct = 0; ct < 5; ++ct)
            acc[ct] = __builtin_amdgcn_mfma_f32_16x16x32_bf16(a, b[ct], acc[ct], 0, 0, 0);
    }
    int rhi = lane >> 4;
#pragma unroll
    for (int ct = 0; ct < 5; ++ct) {
        int col = c0 + ct * 16 + rlo;
        if (col >= H) continue;
        float bv = bias[col];
#pragma unroll
        for (int j = 0; j < 4; ++j) {
            int r = row0 + rhi * 4 + j;
            float v = acc[ct][j] + bv;
            if (mat == 1) nodeV_bf[(size_t)r * H + col] = __float2bfloat16(v);
            else          out[(size_t)r * H + col] = v;
        }
    }
}

// ---- K2 fused: edge gate GEMM (bx<1000) || CSR gather (bx>=1000, 1 node/block)
__global__ __launch_bounds__(256) void fused_mid(const bf16* __restrict__ edge_bf,
                                                 const bf16* __restrict__ WtK_l,
                                                 const float* __restrict__ nodeU,
                                                 const int* __restrict__ msrc,
                                                 const int* __restrict__ mdst,
                                                 bf16* __restrict__ gate_bf,
                                                 float* __restrict__ REc,
                                                 const bf16* __restrict__ nodeV_bf,
                                                 const float* __restrict__ nodeUn,
                                                 const int* __restrict__ offs,
                                                 const float* __restrict__ invS,
                                                 float* __restrict__ RNc,
                                                 float* __restrict__ aggv) {
    __shared__ bf16 smA[32 * 320];         // 20 KB
    int tid = threadIdx.x;
    int bx = blockIdx.x;
    if (bx < 1000) {
        int wave = tid >> 6, lane = tid & 63;
        int row0 = bx * 32;
        int c0 = wave * 80;
        int rlo = lane & 15, khi = lane >> 4, rhi = lane >> 4;

        // hoist permuted src/dst loads (coalesced)
        int se_[8], de_[8];
#pragma unroll
        for (int rt = 0; rt < 2; ++rt)
#pragma unroll
            for (int j = 0; j < 4; ++j) {
                int r = row0 + rt * 16 + rhi * 4 + j;
                se_[rt * 4 + j] = msrc[r];
                de_[rt * 4 + j] = mdst[r];
            }

        // stage A: fully coalesced 20480B contiguous span, XOR-swizzled
        const uint4* Ag = (const uint4*)(edge_bf + (size_t)row0 * HP);
#pragma unroll
        for (int it = 0; it < 5; ++it) {
            int cid = it * 256 + tid;      // 0..1279
            int row = cid / 40, ch = cid % 40;
            uint4 v = Ag[cid];
            *(uint4*)(smA + row * 320 + ((ch ^ (row & 7)) << 3)) = v;
        }
        __syncthreads();

        const bf16* Bw = WtK_l + (size_t)wave * 25600;
        f32x4 acc[2][5];
#pragma unroll
        for (int rt = 0; rt < 2; ++rt)
#pragma unroll
            for (int ct = 0; ct < 5; ++ct) acc[rt][ct] = (f32x4)0.f;
#pragma unroll 2
        for (int ks = 0; ks < 10; ++ks) {
            int c = ks * 4 + khi;
            int kcb = (ks * 4 + khi) * 80;
            bf16x8 a[2], b[5];
#pragma unroll
            for (int rt = 0; rt < 2; ++rt) {
                int row = rt * 16 + rlo;
                a[rt] = *(const bf16x8*)(smA + row * 320 + ((c ^ (row & 7)) << 3));
            }
#pragma unroll
            for (int ct = 0; ct < 5; ++ct)
                b[ct] = *(const bf16x8*)(Bw + (size_t)(kcb + ct * 16 + rlo) * 8);
#pragma unroll
            for (int rt = 0; rt < 2; ++rt)
#pragma unroll
                for (int ct = 0; ct < 5; ++ct)
                    acc[rt][ct] = __builtin_amdgcn_mfma_f32_16x16x32_bf16(a[rt], b[ct], acc[rt][ct], 0, 0, 0);
        }
        float csum[5], csq[5];
#pragma unroll
        for (int ct = 0; ct < 5; ++ct) { csum[ct] = 0.f; csq[ct] = 0.f; }
#pragma unroll
        for (int rt = 0; rt < 2; ++rt)
#pragma unroll
            for (int j = 0; j < 4; ++j) {
                int r = row0 + rt * 16 + rhi * 4 + j;
                int se = se_[rt * 4 + j], de = de_[rt * 4 + j];
#pragma unroll
                for (int ct = 0; ct < 5; ++ct) {
                    int col = c0 + ct * 16 + rlo;
                    if (col < H) {
                        float g = acc[rt][ct][j] + nodeU[(size_t)se * H + col] + nodeU[(size_t)de * H + col];
                        gate_bf[(size_t)r * H + col] = __float2bfloat16(g);
                        csum[ct] += g;
                        csq[ct] += g * g;
                    }
                }
            }
#pragma unroll
        for (int ct = 0; ct < 5; ++ct) {
            csum[ct] += __shfl_xor(csum[ct], 16, 64);
            csum[ct] += __shfl_xor(csum[ct], 32, 64);
            csq[ct]  += __shfl_xor(csq[ct], 16, 64);
            csq[ct]  += __shfl_xor(csq[ct], 32, 64);
        }
        if (khi == 0) {
            float* re = REc + (size_t)(bx & (NREP - 1)) * RSTRIDE;
#pragma unroll
            for (int ct = 0; ct < 5; ++ct) {
                int col = c0 + ct * 16 + rlo;
                if (col < H) {
                    atomicAdd(&re[col], csum[ct]);
                    atomicAdd(&re[SSTRIDE + col], csq[ct]);
                }
            }
        }
    } else {
        // ------- CSR gather: 1 node/block; contiguous rows; 4x unrolled ILP
        int n = bx - 1000;                 // 0..1999
        int h0 = tid;
        bool has1 = (tid < H - 256);
        int h1 = 256 + tid;
        float inv0 = invS[h0];
        float inv1 = has1 ? invS[h1] : 0.f;
        int beg = offs[n], end = offs[n + 1];
        float a0 = 0.f, a1 = 0.f, a2 = 0.f, a3 = 0.f;
        float b0 = 0.f, b1 = 0.f, b2 = 0.f, b3 = 0.f;
        int i = beg;
        for (; i + 4 <= end; i += 4) {
            int s0 = msrc[i], s1_ = msrc[i + 1], s2_ = msrc[i + 2], s3_ = msrc[i + 3];
            const bf16* e0 = edge_bf + (size_t)(i + 0) * HP;
            const bf16* e1 = edge_bf + (size_t)(i + 1) * HP;
            const bf16* e2 = edge_bf + (size_t)(i + 2) * HP;
            const bf16* e3 = edge_bf + (size_t)(i + 3) * HP;
            const bf16* v0 = nodeV_bf + (size_t)s0 * H;
            const bf16* v1 = nodeV_bf + (size_t)s1_ * H;
            const bf16* v2 = nodeV_bf + (size_t)s2_ * H;
            const bf16* v3 = nodeV_bf + (size_t)s3_ * H;
            float x0 = __bfloat162float(e0[h0]);
            float x1 = __bfloat162float(e1[h0]);
            float x2 = __bfloat162float(e2[h0]);
            float x3 = __bfloat162float(e3[h0]);
            a0 += sigm(x0) * __bfloat162float(v0[h0]);
            a1 += sigm(x1) * __bfloat162float(v1[h0]);
            a2 += sigm(x2) * __bfloat162float(v2[h0]);
            a3 += sigm(x3) * __bfloat162float(v3[h0]);
            if (has1) {
                float y0 = __bfloat162float(e0[h1]);
                float y1 = __bfloat162float(e1[h1]);
                float y2 = __bfloat162float(e2[h1]);
                float y3 = __bfloat162float(e3[h1]);
                b0 += sigm(y0) * __bfloat162float(v0[h1]);
                b1 += sigm(y1) * __bfloat162float(v1[h1]);
                b2 += sigm(y2) * __bfloat162float(v2[h1]);
                b3 += sigm(y3) * __bfloat162float(v3[h1]);
            }
        }
        for (; i < end; ++i) {
            int s = msrc[i];
            const bf16* er = edge_bf + (size_t)i * HP;
            const bf16* vr = nodeV_bf + (size_t)s * H;
            a0 += sigm(__bfloat162float(er[h0])) * __bfloat162float(vr[h0]);
            if (has1) b0 += sigm(__bfloat162float(er[h1])) * __bfloat162float(vr[h1]);
        }
        float a = (a0 + a1) + (a2 + a3);
        size_t nbase = (size_t)n * H;
        float v0s = nodeUn[nbase + h0] + a * inv0;
        aggv[nbase + h0] = v0s;
        float* rn = RNc + (size_t)(n & (NREP - 1)) * RSTRIDE;
        atomicAdd(&rn[h0], v0s);
        atomicAdd(&rn[SSTRIDE + h0], v0s * v0s);
        if (has1) {
            float bsum = (b0 + b1) + (b2 + b3);
            float v1s = nodeUn[nbase + h1] + bsum * inv1;
            aggv[nbase + h1] = v1s;
            atomicAdd(&rn[h1], v1s);
            atomicAdd(&rn[SSTRIDE + h1], v1s * v1s);
        }
    }
}

// ------------- K3: edge_finalize (bx<NEB) || node_update (bx>=NEB), bf16 residual
__global__ __launch_bounds__(256) void fused_final(bf16* __restrict__ edge_bf,
                                                   const bf16* __restrict__ gate_bf,
                                                   const float* __restrict__ REc,
                                                   float* __restrict__ REo,
                                                   const float* __restrict__ RNc,
                                                   float* __restrict__ RNo,
                                                   float* __restrict__ RSnext,
                                                   const float* __restrict__ eg,
                                                   const float* __restrict__ ebt,
                                                   const float* __restrict__ ng,
                                                   const float* __restrict__ nbt,
                                                   float* __restrict__ node,
                                                   bf16* __restrict__ node_bf,
                                                   const float* __restrict__ aggv) {
    __shared__ float sc_s[SSTRIDE], of_s[SSTRIDE], s_s[SSTRIDE];
    int bx = blockIdx.x, t = threadIdx.x;
    if (bx < NEB) {
        const float invE = 1.f / N_EDGES;
        for (int i = t; i < SSTRIDE; i += 256) {
            s_s[i] = 0.f;
            if (i < H) {
                float gs = 0.f, gq = 0.f;
#pragma unroll 8
                for (int r = 0; r < NREP; ++r) {
                    gs += REc[r * RSTRIDE + i];
                    gq += REc[r * RSTRIDE + SSTRIDE + i];
                }
                float mean = gs * invE;
                float var = fmaxf(gq * invE - mean * mean, 0.f);
                float rstd = rsqrtf(var + 1e-5f);
                float sc = rstd * eg[i];
                sc_s[i] = sc;
                of_s[i] = ebt[i] - mean * sc;
            }
        }
        __syncthreads();
        int hc = t % 80, rgrp = t / 80;
        bool act = (hc < CH) && (rgrp < 3);
        float ss[4] = {0.f, 0.f, 0.f, 0.f};
        int col0 = hc * 4;
        if (act) {
            float sc[4], of[4];
#pragma unroll
            for (int j = 0; j < 4; ++j) { sc[j] = sc_s[col0 + j]; of[j] = of_s[col0 + j]; }
            int e0 = bx * 64;
            for (int r = rgrp; r < 64; r += 3) {
                int e = e0 + r;
                union { ushort4 u; bf16 b[4]; } eb, gv, ob;
                eb.u = *(const ushort4*)(edge_bf + (size_t)e * HP + col0);
                gv.u = *(const ushort4*)(gate_bf + (size_t)e * H + col0);
#pragma unroll
                for (int j = 0; j < 4; ++j) {
                    float g = __bfloat162float(gv.b[j]);
                    float val = fmaxf(fmaf(g, sc[j], of[j]), 0.f);
                    float nv = __bfloat162float(eb.b[j]) + val;
                    ob.b[j] = __float2bfloat16(nv);
                    ss[j] += sigm(__bfloat162float(ob.b[j]));
                }
                *(ushort4*)(edge_bf + (size_t)e * HP + col0) = ob.u;
            }
#pragma unroll
            for (int j = 0; j < 4; ++j) atomicAdd(&s_s[col0 + j], ss[j]);
        }
        __syncthreads();
        float* rs = RSnext + (size_t)(bx & (NREP - 1)) * SSTRIDE;
        for (int i = t; i < H; i += 256) atomicAdd(&rs[i], s_s[i]);
    } else {
        int idx = bx - NEB;                // 0..NUB-1
        if (idx < NREP) {
            for (int i = t; i < RSTRIDE; i += 256) {
                REo[(size_t)idx * RSTRIDE + i] = 0.f;
                RNo[(size_t)idx * RSTRIDE + i] = 0.f;
            }
        }
        const float invN = 1.f / N_NODES;
        for (int i = t; i < H; i += 256) {
            float ns = 0.f, nq = 0.f;
#pragma unroll 8
            for (int r = 0; r < NREP; ++r) {
                ns += RNc[r * RSTRIDE + i];
                nq += RNc[r * RSTRIDE + SSTRIDE + i];
            }
            float mean = ns * invN;
            float var = fmaxf(nq * invN - mean * mean, 0.f);
            float rstd = rsqrtf(var + 1e-5f);
            float sc = rstd * ng[i];
            sc_s[i] = sc;
            of_s[i] = nbt[i] - mean * sc;
        }
        __syncthreads();
#pragma unroll
        for (int it = 0; it < 4; ++it) {
            int c = idx * 1024 + it * 256 + t;
            if (c >= NH / 4) break;
            int n = c / CH, hc = c % CH, col0 = hc * 4;
            float4 v4 = ((const float4*)aggv)[c];
            float4 nd = ((const float4*)node)[c];
            const float* v4p = (const float*)&v4;
            const float* ndp = (const float*)&nd;
            union { ushort4 u; bf16 b[4]; } ob;
            float outv[4];
#pragma unroll
            for (int j = 0; j < 4; ++j) {
                float g = fmaf(v4p[j], sc_s[col0 + j], of_s[col0 + j]);
                outv[j] = ndp[j] + fmaxf(g, 0.f);
                ob.b[j] = __float2bfloat16(outv[j]);
            }
            ((float4*)node)[c] = make_float4(outv[0], outv[1], outv[2], outv[3]);
            *(ushort4*)(node_bf + (size_t)n * HP + col0) = ob.u;
        }
    }
}

// ----------------- classifier + loss (sorted rows; map back via eidx)
__global__ __launch_bounds__(256) void classify_loss(const bf16* __restrict__ edge_bf,
                                                     const float* __restrict__ clsW,
                                                     const float* __restrict__ clsb,
                                                     const int* __restrict__ eidx,
                                                     const int* __restrict__ msrc,
                                                     const int* __restrict__ mdst,
                                                     const float* __restrict__ y,
                                                     float* __restrict__ out) {
    __shared__ float wl[4];
    int lane = threadIdx.x & 63;
    int wid = threadIdx.x >> 6;
    int quad = lane >> 2;
    int ql = lane & 3;
    float w[80];
#pragma unroll
    for (int j = 0; j < 80; ++j) {
        int col = ql * 80 + j;
        w[j] = (col < H) ? clsW[col] : 0.f;
    }
    int g = blockIdx.x * 4 + wid;
    int q = g * 16 + quad;             // sorted row index
    const bf16* row = edge_bf + (size_t)q * HP + ql * 80;
    float acc = 0.f;
#pragma unroll
    for (int v = 0; v < 10; ++v) {
        bf16x8 bv = *(const bf16x8*)(row + v * 8);
#pragma unroll
        for (int j = 0; j < 8; ++j)
            acc += __bfloat162float(((const bf16*)&bv)[j]) * w[v * 8 + j];
    }
    acc += __shfl_xor(acc, 1, 64);
    acc += __shfl_xor(acc, 2, 64);
    float lsum = 0.f;
    if (ql == 0) {
        float z = acc + clsb[0];
        float p = 1.f / (1.f + __expf(-z));
        atomicAdd(&out[(size_t)msrc[q] * N_NODES + mdst[q]], p);
        float yv = y[eidx[q]];
        float pc = fminf(fmaxf(p, 1e-7f), 1.f - 1e-7f);
        lsum = -(yv * __logf(pc) + (1.f - yv) * log1pf(-pc));
    }
#pragma unroll
    for (int off = 32; off > 0; off >>= 1) lsum += __shfl_down(lsum, off, 64);
    if (lane == 0) wl[wid] = lsum;
    __syncthreads();
    if (threadIdx.x == 0) {
        float tt = wl[0] + wl[1] + wl[2] + wl[3];
        atomicAdd(&out[(size_t)N_NODES * N_NODES], tt * (1.f / N_EDGES));
    }
}

// ---------------------------------------------------------------- launcher
extern "C" void kernel_launch(void* const* d_in, const int* in_sizes, int n_in,
                              void* d_out, int out_size, void* d_ws, size_t ws_size,
                              hipStream_t stream) {
    const float* x          = (const float*)d_in[0];
    const float* edge_attr  = (const float*)d_in[1];
    const int*   edge_index = (const int*)d_in[2];
    const float* y          = (const float*)d_in[3];
    const float* node_emb_W = (const float*)d_in[4];
    const float* node_emb_b = (const float*)d_in[5];
    const float* edge_d_W   = (const float*)d_in[6];
    const float* edge_d_b   = (const float*)d_in[7];
    const float* edge_t_W   = (const float*)d_in[8];
    const float* edge_t_b   = (const float*)d_in[9];
    const float* eU_W = (const float*)d_in[10];
    const float* eU_b = (const float*)d_in[11];
    const float* eW_W = (const float*)d_in[12];
    const float* nU_W = (const float*)d_in[14];
    const float* nU_b = (const float*)d_in[15];
    const float* nV_W = (const float*)d_in[16];
    const float* nV_b = (const float*)d_in[17];
    const float* bn_e_g = (const float*)d_in[18];
    const float* bn_e_b = (const float*)d_in[19];
    const float* bn_n_g = (const float*)d_in[20];
    const float* bn_n_b = (const float*)d_in[21];
    const float* cls_W = (const float*)d_in[22];
    const float* cls_b = (const float*)d_in[23];

    const int* src = edge_index;
    const int* dst = edge_index + N_EDGES;

    float* ws     = (float*)d_ws;
    float* node   = ws;                  // NH
    float* nodeU  = node + NH;           // NH
    float* nodeV  = nodeU + NH;          // NH (bf16 actually; reuse slot)
    float* nodeUn = nodeV + NH;          // NH
    float* aggv   = nodeUn + NH;         // NH
    float* RE2    = aggv + NH;           // 2 x 32*608   <-- zero region start
    float* RN2    = RE2 + 2 * NREP * RSTRIDE;
    float* RS2    = RN2 + 2 * NREP * RSTRIDE;  // 2 x 32*304
    float* invS   = RS2 + 2 * NREP * SSTRIDE;  // 304
    bf16* nodeV_bf = (bf16*)nodeV;                        // 2000*300 bf16 (in nodeV slot)
    bf16* node_bf = (bf16*)(invS + SSTRIDE);              // 2048*320
    bf16* edge_bf = node_bf + (size_t)NODE_ROWS_PAD * HP; // 32000*320 (sorted order)
    bf16* gate_bf = edge_bf + (size_t)N_EDGES * HP;       // 32000*300 (not zeroed)
    bf16* WtK_all = gate_bf + (size_t)N_EDGES * H;        // 120*102400 (K-packed)
    int* csr_counts = (int*)(WtK_all + (size_t)120 * WMAT);
    int* csr_offs   = csr_counts + 2048;
    int* csr_woff   = csr_offs + 2048;
    int* csr_eidx   = csr_woff + 2048;                     // 32000
    int* csr_msrc   = csr_eidx + N_EDGES;                  // 32000
    int* csr_mdst   = csr_msrc + N_EDGES;                  // 32000

    float* out = (float*)d_out;

    // zero: out, [RE2 | RN2 | RS2 | invS | node_bf | edge_bf], csr_counts
    int zstats = 4 * NREP * RSTRIDE + 2 * NREP * SSTRIDE + SSTRIDE;
    int zlen = zstats + (NODE_ROWS_PAD * HP + N_EDGES * HP) / 2;
    zero_buf<<<(N_NODES * N_NODES + 1 + 255) / 256, 256, 0, stream>>>(out, N_NODES * N_NODES + 1);
    zero_buf<<<(zlen + 255) / 256, 256, 0, stream>>>(RE2, zlen);
    zero_buf<<<8, 256, 0, stream>>>((float*)csr_counts, 2048);

    convert_weights_k<<<12000, 256, 0, stream>>>(eU_W, eW_W, nU_W, nV_W, WtK_all);
    csr_hist<<<(N_EDGES + 255) / 256, 256, 0, stream>>>(dst, csr_counts);
    csr_scan<<<1, 256, 0, stream>>>(csr_counts, csr_offs, csr_woff);
    csr_scatter<<<(N_EDGES + 255) / 256, 256, 0, stream>>>(src, dst, csr_woff,
                                                           csr_eidx, csr_msrc, csr_mdst);
    node_embed<<<(NH + 255) / 256, 256, 0, stream>>>(x, node_emb_W, node_emb_b, node, node_bf);
    edge_embed<<<NEB, 256, 0, stream>>>(edge_attr, csr_eidx, edge_d_W, edge_d_b,
                                        edge_t_W, edge_t_b, edge_bf, RS2);

    for (int l = 0; l < NLAYERS; ++l) {
        float* REc = RE2 + (size_t)(l & 1) * NREP * RSTRIDE;
        float* REo = RE2 + (size_t)((l + 1) & 1) * NREP * RSTRIDE;
        float* RNc = RN2 + (size_t)(l & 1) * NREP * RSTRIDE;
        float* RNo = RN2 + (size_t)((l + 1) & 1) * NREP * RSTRIDE;
        float* RScur = RS2 + (size_t)(l & 1) * NREP * SSTRIDE;
        float* RSnxt = RS2 + (size_t)((l + 1) & 1) * NREP * SSTRIDE;
        const bf16* WtK_e = WtK_all + (size_t)(30 + l) * WMAT;

        gemm_node<<<1505, 64, 0, stream>>>(node_bf, WtK_all, eU_b, nV_b, nU_b, l,
                                           nodeU, nodeV_bf, nodeUn, RScur, RSnxt, invS);
        fused_mid<<<3000, 256, 0, stream>>>(edge_bf, WtK_e, nodeU, csr_msrc, csr_mdst,
                                            gate_bf, REc,
                                            nodeV_bf, nodeUn, csr_offs,
                                            invS, RNc, aggv);
        fused_final<<<NEB + NUB, 256, 0, stream>>>(edge_bf, gate_bf,
                                                   REc, REo, RNc, RNo, RSnxt,
                                                   bn_e_g + l * H, bn_e_b + l * H,
                                                   bn_n_g + l * H, bn_n_b + l * H,
                                                   node, node_bf, aggv);
    }

    classify_loss<<<500, 256, 0, stream>>>(edge_bf, cls_W, cls_b,
                                           csr_eidx, csr_msrc, csr_mdst, y, out);
}